// Round 7
// baseline (468.647 us; speedup 1.0000x reference)
//
#include <hip/hip_runtime.h>
#include <math.h>

#define NROW 16384   // B*N rows
#define NCOL 4096
#define CDIM 256
#define DKDIM 64
#define SCALE 0.125f // DK^-0.5

typedef float v4f __attribute__((ext_vector_type(4)));
typedef __attribute__((ext_vector_type(8))) short short8v;  // 8 bf16 = 4 VGPR
typedef __attribute__((ext_vector_type(4))) float f32x4;

// ---- monotone float<->u32 key helpers (unsigned compare == float compare) ----
__device__ __forceinline__ unsigned mono(float v) {
  unsigned u = __float_as_uint(v);
  unsigned s = (unsigned)(((int)u) >> 31);
  return u ^ (s | 0x80000000u);
}
__device__ __forceinline__ float unmono(unsigned k) {
  unsigned u = (k & 0x80000000u) ? (k ^ 0x80000000u) : ~k;
  return __uint_as_float(u);
}
__device__ __forceinline__ unsigned short f2bf(float f) {  // RNE bf16
  unsigned u = __float_as_uint(f);
  u += 0x7FFFu + ((u >> 16) & 1u);
  return (unsigned short)(u >> 16);
}
__device__ __forceinline__ unsigned umaxu(unsigned a, unsigned b) { return a > b ? a : b; }

// ---- top-8 maintenance on packed keys (proven group-of-8 insert logic) ----
// Used only in phase 2 (phase 1 is pure oct-max, no selection).
__device__ __forceinline__ void ins8(unsigned tk[8], unsigned& tmin, int& tmpos, unsigned v) {
  #pragma unroll
  for (int j = 0; j < 8; ++j) if (j == tmpos) tk[j] = v;
  tmin = tk[0]; tmpos = 0;
  #pragma unroll
  for (int j = 1; j < 8; ++j) if (tk[j] < tmin) { tmin = tk[j]; tmpos = j; }
}
__device__ __forceinline__ unsigned umax8(const unsigned kv[8]) {
  unsigned a = umaxu(umaxu(kv[0], kv[1]), umaxu(kv[2], kv[3]));
  unsigned b = umaxu(umaxu(kv[4], kv[5]), umaxu(kv[6], kv[7]));
  return umaxu(a, b);
}
__device__ __forceinline__ void seed8r(const unsigned kv[8],
                                       unsigned tk[8], unsigned& tmin, int& tmpos) {
  #pragma unroll
  for (int j = 0; j < 8; ++j) tk[j] = kv[j];
  tmin = tk[0]; tmpos = 0;
  #pragma unroll
  for (int j = 1; j < 8; ++j) if (tk[j] < tmin) { tmin = tk[j]; tmpos = j; }
}
__device__ __forceinline__ void scan8r(const unsigned kvin[8],
                                       unsigned tk[8], unsigned& tmin, int& tmpos) {
  unsigned kv[8];
  #pragma unroll
  for (int j = 0; j < 8; ++j) kv[j] = kvin[j];
  unsigned gm = umax8(kv);
  #pragma unroll
  for (int pass = 0; pass < 2; ++pass) {
    if (__any(gm > tmin)) {            // wave-uniform branch
      if (gm > tmin) {                 // per-lane insert (keys unique by oct id)
        ins8(tk, tmin, tmpos, gm);
        #pragma unroll
        for (int j = 0; j < 8; ++j) if (kv[j] == gm) kv[j] = 0u;
      }
      gm = umax8(kv);
    }
  }
  if (__any(gm > tmin)) {              // rare: >=3 qualifiers in this group
    #pragma unroll
    for (int j = 0; j < 8; ++j) if (kv[j] > tmin) ins8(tk, tmin, tmpos, kv[j]);
  }
}

// LDS key array XOR swizzle (u32 granularity, keeps uint4 alignment):
// bijective (XOR touches bits 2-4 only; off>>6 untouched); spreads the
// stride-64 phase-2 reads across bank groups.
__device__ __forceinline__ int kswz(int row, int off) {
  return row * 512 + (off ^ (((off >> 6) & 7) << 2));
}
__device__ __forceinline__ void ld8swz(const unsigned* k, int row, int off,
                                       unsigned kv[8]) {
  uint4 ka = *(const uint4*)&k[kswz(row, off)];
  uint4 kb = *(const uint4*)&k[kswz(row, off + 4)];
  kv[0] = ka.x; kv[1] = ka.y; kv[2] = ka.z; kv[3] = ka.w;
  kv[4] = kb.x; kv[5] = kb.y; kv[6] = kb.z; kv[7] = kb.w;
}

// ---------------- Kernel 1: fused Q/K projection (fp32 + bf16 row-major) ----
__global__ __launch_bounds__(512, 2) void qk_proj(
    const float* __restrict__ x, const float* __restrict__ Wq,
    const float* __restrict__ Wk, float* __restrict__ Qt,
    float* __restrict__ Kt, unsigned short* __restrict__ Qh,
    unsigned short* __restrict__ Kh) {
  __shared__ float4 xs4[64][65];  // row stride 65 f4-units -> bank-group spread
  const int t = threadIdx.x;
  const int rb = blockIdx.x;      // 256 blocks of 64 rows
  {
    const float4* xg = (const float4*)(x + (size_t)rb * 64 * CDIM);
    #pragma unroll
    for (int i = 0; i < 8; ++i) {
      int idx = i * 512 + t;      // 0..4095
      xs4[idx >> 6][idx & 63] = xg[idx];
    }
  }
  __syncthreads();

  const int lane = t & 63;
  const int wu = __builtin_amdgcn_readfirstlane(t >> 6);  // wave id, uniform
  const int proj = wu >> 2;
  const int chunk = wu & 3;       // d-chunk: d = chunk*16 .. +15
  const float* __restrict__ Wp = proj ? Wk : Wq;

  float acc[16];
  #pragma unroll
  for (int j = 0; j < 16; ++j) acc[j] = 0.f;

  #pragma unroll 4
  for (int cs = 0; cs < 64; ++cs) {        // 4 c's per step
    float4 xv = xs4[lane][cs];
    const float xc[4] = {xv.x, xv.y, xv.z, xv.w};
    #pragma unroll
    for (int i = 0; i < 4; ++i) {
      const float4* __restrict__ w4 =
          (const float4*)(Wp + (size_t)(cs * 4 + i) * DKDIM + chunk * 16);
      float4 wa = w4[0], wb = w4[1], wc = w4[2], wd = w4[3];
      float xi = xc[i];
      acc[0]  = fmaf(xi, wa.x, acc[0]);  acc[1]  = fmaf(xi, wa.y, acc[1]);
      acc[2]  = fmaf(xi, wa.z, acc[2]);  acc[3]  = fmaf(xi, wa.w, acc[3]);
      acc[4]  = fmaf(xi, wb.x, acc[4]);  acc[5]  = fmaf(xi, wb.y, acc[5]);
      acc[6]  = fmaf(xi, wb.z, acc[6]);  acc[7]  = fmaf(xi, wb.w, acc[7]);
      acc[8]  = fmaf(xi, wc.x, acc[8]);  acc[9]  = fmaf(xi, wc.y, acc[9]);
      acc[10] = fmaf(xi, wc.z, acc[10]); acc[11] = fmaf(xi, wc.w, acc[11]);
      acc[12] = fmaf(xi, wd.x, acc[12]); acc[13] = fmaf(xi, wd.y, acc[13]);
      acc[14] = fmaf(xi, wd.z, acc[14]); acc[15] = fmaf(xi, wd.w, acc[15]);
    }
  }

  const int gr = rb * 64 + lane;  // global row
  float* Of = (proj ? Kt : Qt) + (size_t)gr * 64 + chunk * 16;
  #pragma unroll
  for (int i = 0; i < 4; ++i) {
    float4 o = {acc[4 * i], acc[4 * i + 1], acc[4 * i + 2], acc[4 * i + 3]};
    ((float4*)Of)[i] = o;
  }
  unsigned short* Oh = (proj ? Kh : Qh) + (size_t)gr * 64 + chunk * 16;
  unsigned hp[8];
  #pragma unroll
  for (int i = 0; i < 8; ++i)
    hp[i] = (unsigned)f2bf(acc[2 * i]) | ((unsigned)f2bf(acc[2 * i + 1]) << 16);
  uint4 h0 = {hp[0], hp[1], hp[2], hp[3]};
  uint4 h1 = {hp[4], hp[5], hp[6], hp[7]};
  ((uint4*)Oh)[0] = h0;
  ((uint4*)Oh)[1] = h1;
}

// ---------------- Kernel 2: FUSED, oct-max funnel (depth 16) ----------------
// Block = 16 rows x 4096 cols, 4 waves (wave wu owns cols wu*1024..+1023).
// Oct = 8 cols {wu*1024 + g*128 + t8*16 + l15 : t8}. A bf16-rank-r element's
// oct is beaten by <= r-1 octs, so TOP-16 octs cover the bf16-top-16 (and the
// bf16-top-8 coverage survives phase-2's span funnel unconditionally). Depth
// 16 is the r6 fix: a bf16 rank-8/9 noise inversion no longer drops the true
// top-8 element -- missing one now needs a >30-sigma bf16 error.
// Phase 1: MFMA + running oct-max (7 v_max per 8 values, NO selection) ->
//          512 oct-keys/row (23-bit value | 9-bit oct id) in swizzled LDS.
// Phase 2: proven scan8r funnel, 8 lanes/row x 64 keys -> 64 survivors/row.
// Phase 3: shuffle-extract top-16 octs; 4 lanes/oct, 2 cols/lane -> 128
//          exact fp32 dots (same fma order), exact top-8 + softmax.
// Phase 4: NT zero-fill + vmcnt(0) + sparse patch; same-wave rows, no barrier.
__global__ __launch_bounds__(256, 4) void s_fused(
    const unsigned short* __restrict__ Qh, const unsigned short* __restrict__ Kh,
    const float* __restrict__ Qt, const float* __restrict__ Kt,
    float* __restrict__ out) {
  __shared__ unsigned keys[16 * 512];   // 32 KB, XOR-swizzled oct-keys
  __shared__ unsigned cand[16][64];     // 4 KB survivors
  float (*pval)[8] = (float(*)[8])keys;          // overlay (keys dead after ph2)
  int   (*pcol)[8] = (int(*)[8])(keys + 128);

  const int t = threadIdx.x;
  const int lane = t & 63;
  const int wu = __builtin_amdgcn_readfirstlane(t >> 6);
  // XCD-chunked bijective swizzle (1024 = 8*128)
  const int bid = blockIdx.x;
  const int orig = (bid & 7) * 128 + (bid >> 3);
  const int blockrow = orig * 16;  // global row base
  const int b = blockrow >> 12;    // batch

  const int l15 = lane & 15, lk = lane >> 4;
  // A-fragments: the block's 16 Q rows. row = lane&15, k = (lane>>4)*8+j.
  const int rowg = blockrow + l15;
  const short8v a0 = *(const short8v*)(Qh + (size_t)rowg * 64 + lk * 8);
  const short8v a1 = *(const short8v*)(Qh + (size_t)rowg * 64 + lk * 8 + 32);
  const unsigned short* Kb = Kh + ((size_t)(b << 12)) * 64;

  // ---- Phase 1: MFMA + oct-max over my 1024-col slice (no selection) ----
  unsigned okey[4][8];             // [stream i][group g]
  #pragma unroll 1
  for (int g = 0; g < 8; ++g) {
    float om[4];
    #pragma unroll
    for (int t8 = 0; t8 < 8; ++t8) {
      const int col = wu * 1024 + g * 128 + t8 * 16 + l15;
      const unsigned short* kp = Kb + (size_t)col * 64 + lk * 8;
      const short8v b0 = *(const short8v*)(kp);        // B: col=lane&15, k-half 0
      const short8v b1 = *(const short8v*)(kp + 32);   // k-half 1
      f32x4 acc = {0.f, 0.f, 0.f, 0.f};
      acc = __builtin_amdgcn_mfma_f32_16x16x32_bf16(a0, b0, acc, 0, 0, 0);
      acc = __builtin_amdgcn_mfma_f32_16x16x32_bf16(a1, b1, acc, 0, 0, 0);
      // C/D: col=lane&15, row=(lane>>4)*4+i (m89-verified)
      #pragma unroll
      for (int i = 0; i < 4; ++i)
        om[i] = (t8 == 0) ? acc[i] : fmaxf(om[i], acc[i]);
    }
    const unsigned oid = (unsigned)(((wu * 8 + g) << 4) | l15);  // 9 bits
    #pragma unroll
    for (int i = 0; i < 4; ++i)
      okey[i][g] = (mono(om[i]) & 0xFFFFFE00u) | oid;  // 23 value bits
  }
  #pragma unroll
  for (int i = 0; i < 4; ++i) {    // write 8 oct-keys per stream
    const int row = lk * 4 + i;
    const int off = wu * 128 + l15 * 8;
    uint4 s0 = {okey[i][0], okey[i][1], okey[i][2], okey[i][3]};
    uint4 s1 = {okey[i][4], okey[i][5], okey[i][6], okey[i][7]};
    *(uint4*)&keys[kswz(row, off)] = s0;
    *(uint4*)&keys[kswz(row, off + 4)] = s1;
  }
  __syncthreads();

  // ---- Phase 2: 8 scan-lanes/row, each scans a 64-key span -> 64 surv/row --
  if ((t & 15) < 8) {
    const int row = t >> 4, s = t & 7;
    const int base = s * 64;
    unsigned kv[8]; unsigned mt[8]; unsigned mmin; int mmpos;
    ld8swz(keys, row, base, kv);
    seed8r(kv, mt, mmin, mmpos);
    #pragma unroll
    for (int m = 1; m < 8; ++m) {
      ld8swz(keys, row, base + m * 8, kv);
      scan8r(kv, mt, mmin, mmpos);
    }
    uint4 o0 = {mt[0], mt[1], mt[2], mt[3]};
    uint4 o1 = {mt[4], mt[5], mt[6], mt[7]};
    uint4* cp = (uint4*)(&cand[row][s * 8]);
    cp[0] = o0; cp[1] = o1;
  }
  __syncthreads();

  // ---- Phase 3: top-16 octs -> 128 cols -> exact recompute + softmax ----
  #pragma unroll 1
  for (int p = 0; p < 4; ++p) {
    const int rr = p * 4 + wu;     // my wave's row this pass
    unsigned ok = cand[rr][lane];
    const int q2 = lane >> 2, e2 = lane & 3;  // oct rank / col pair within oct
    unsigned mykey = 0u;
    #pragma unroll
    for (int it = 0; it < 16; ++it) {  // branchless: keys unique -> self-zero
      unsigned m = ok;
      #pragma unroll
      for (int d = 1; d < 64; d <<= 1) m = umaxu(m, (unsigned)__shfl_xor((int)m, d, 64));
      if (q2 == it) mykey = m;         // lane group q2 takes winner #it
      if (ok == m) ok = 0u;
    }
    const unsigned oid = mykey & 0x1FFu;
    const int colb = (int)((oid >> 4) * 128 + (oid & 15u));
    const int col0 = colb + e2 * 16;   // t8 = e2
    const int col1 = col0 + 64;        // t8 = e2 + 4
    const float4* Kp0 = (const float4*)(Kt + ((size_t)((b << 12) + col0)) * 64);
    const float4* Kp1 = (const float4*)(Kt + ((size_t)((b << 12) + col1)) * 64);
    const float4* Qp = (const float4*)(Qt + (size_t)(blockrow + rr) * 64);  // uniform
    float s0 = 0.f, s1 = 0.f;
    #pragma unroll
    for (int g2 = 0; g2 < 16; ++g2) {  // same sequential fma order per column
      float4 qf = Qp[g2];
      float4 k0f = Kp0[g2];
      float4 k1f = Kp1[g2];
      s0 = fmaf(qf.x, k0f.x, s0); s1 = fmaf(qf.x, k1f.x, s1);
      s0 = fmaf(qf.y, k0f.y, s0); s1 = fmaf(qf.y, k1f.y, s1);
      s0 = fmaf(qf.z, k0f.z, s0); s1 = fmaf(qf.z, k1f.z, s1);
      s0 = fmaf(qf.w, k0f.w, s0); s1 = fmaf(qf.w, k1f.w, s1);
    }
    unsigned k0 = mono(s0), k1 = mono(s1);  // full precision: exact ordering
    float vals[8]; int cols[8];
    #pragma unroll
    for (int it = 0; it < 8; ++it) {
      unsigned m = umaxu(k0, k1);
      #pragma unroll
      for (int d = 1; d < 64; d <<= 1) m = umaxu(m, (unsigned)__shfl_xor((int)m, d, 64));
      unsigned long long win = __ballot(k0 == m || k1 == m);
      int wl = (int)__ffsll(win) - 1;
      int mycol = (k0 == m) ? col0 : col1;   // slot resolved on owner lane
      cols[it] = __shfl(mycol, wl, 64);
      vals[it] = unmono(m);
      if (lane == wl) { if (k0 == m) k0 = 0u; else k1 = 0u; }  // exclude winner
    }
    float vq[8]; float sum = 0.f;
    #pragma unroll
    for (int it = 0; it < 8; ++it) { vq[it] = __expf((vals[it] - vals[0]) * SCALE); sum += vq[it]; }
    float inv = 1.f / sum;
    if (lane < 8) {
      pval[rr][lane] = vq[lane] * inv;
      pcol[rr][lane] = cols[lane];
    }
  }
  // no barrier: phase 4 rows {wu, wu+4, wu+8, wu+12} were produced by this wave

  // ---- Phase 4a: pure NT zero-fill of my wave's 4 rows ----
  {
    const v4f z = {0.f, 0.f, 0.f, 0.f};
    #pragma unroll 1
    for (int j = 0; j < 4; ++j) {
      const int sr = wu + 4 * j;
      v4f* orow4 = (v4f*)(out + ((size_t)(blockrow + sr) << 12));
      #pragma unroll
      for (int i = 0; i < 16; ++i)
        __builtin_nontemporal_store(z, &orow4[(size_t)i * 64 + lane]);
    }
  }
  // drain fill stores (per-wave) so the sparse patch lands after them
  asm volatile("s_waitcnt vmcnt(0)" ::: "memory");
  // ---- Phase 4b: sparse patch by the same wave that filled the rows ----
  if (lane < 32) {
    const int sr = wu + 4 * (lane >> 3);
    const int q = lane & 7;
    out[((size_t)(blockrow + sr) << 12) + (size_t)pcol[sr][q]] = pval[sr][q];
  }
}

extern "C" void kernel_launch(void* const* d_in, const int* in_sizes, int n_in,
                              void* d_out, int out_size, void* d_ws, size_t ws_size,
                              hipStream_t stream) {
  const float* x  = (const float*)d_in[0];
  const float* Wq = (const float*)d_in[1];
  const float* Wk = (const float*)d_in[2];
  float* out = (float*)d_out;

  char* ws = (char*)d_ws;                       // 12 MB used
  float* Qt = (float*)ws;                       // 4 MB fp32 [row][64]
  float* Kt = (float*)(ws + ((size_t)4 << 20)); // 4 MB
  unsigned short* Qh = (unsigned short*)(ws + ((size_t)8 << 20));   // 2 MB bf16
  unsigned short* Kh = (unsigned short*)(ws + ((size_t)10 << 20));  // 2 MB

  qk_proj<<<dim3(NROW / 64), 512, 0, stream>>>(x, Wq, Wk, Qt, Kt, Qh, Kh);
  s_fused<<<1024, 256, 0, stream>>>(Qh, Kh, Qt, Kt, out);
}

// Round 9
// 460.796 us; speedup vs baseline: 1.0170x; 1.0170x over previous
//
#include <hip/hip_runtime.h>
#include <math.h>

#define NROW 16384   // B*N rows
#define NCOL 4096
#define CDIM 256
#define DKDIM 64
#define SCALE 0.125f // DK^-0.5

typedef float v4f __attribute__((ext_vector_type(4)));
typedef __attribute__((ext_vector_type(8))) short short8v;  // 8 bf16 = 4 VGPR
typedef __attribute__((ext_vector_type(4))) float f32x4;

// ---- monotone float<->u32 key helpers (unsigned compare == float compare) ----
__device__ __forceinline__ unsigned mono(float v) {
  unsigned u = __float_as_uint(v);
  unsigned s = (unsigned)(((int)u) >> 31);
  return u ^ (s | 0x80000000u);
}
__device__ __forceinline__ float unmono(unsigned k) {
  unsigned u = (k & 0x80000000u) ? (k ^ 0x80000000u) : ~k;
  return __uint_as_float(u);
}
__device__ __forceinline__ unsigned short f2bf(float f) {  // RNE bf16
  unsigned u = __float_as_uint(f);
  u += 0x7FFFu + ((u >> 16) & 1u);
  return (unsigned short)(u >> 16);
}
__device__ __forceinline__ unsigned umaxu(unsigned a, unsigned b) { return a > b ? a : b; }

// ---- top-8 maintenance on packed keys (proven group-of-8 insert logic) ----
// Used only in phase 2 (phase 1 is pure oct-max, no selection).
__device__ __forceinline__ void ins8(unsigned tk[8], unsigned& tmin, int& tmpos, unsigned v) {
  #pragma unroll
  for (int j = 0; j < 8; ++j) if (j == tmpos) tk[j] = v;
  tmin = tk[0]; tmpos = 0;
  #pragma unroll
  for (int j = 1; j < 8; ++j) if (tk[j] < tmin) { tmin = tk[j]; tmpos = j; }
}
__device__ __forceinline__ unsigned umax8(const unsigned kv[8]) {
  unsigned a = umaxu(umaxu(kv[0], kv[1]), umaxu(kv[2], kv[3]));
  unsigned b = umaxu(umaxu(kv[4], kv[5]), umaxu(kv[6], kv[7]));
  return umaxu(a, b);
}
__device__ __forceinline__ void seed8r(const unsigned kv[8],
                                       unsigned tk[8], unsigned& tmin, int& tmpos) {
  #pragma unroll
  for (int j = 0; j < 8; ++j) tk[j] = kv[j];
  tmin = tk[0]; tmpos = 0;
  #pragma unroll
  for (int j = 1; j < 8; ++j) if (tk[j] < tmin) { tmin = tk[j]; tmpos = j; }
}
__device__ __forceinline__ void scan8r(const unsigned kvin[8],
                                       unsigned tk[8], unsigned& tmin, int& tmpos) {
  unsigned kv[8];
  #pragma unroll
  for (int j = 0; j < 8; ++j) kv[j] = kvin[j];
  unsigned gm = umax8(kv);
  #pragma unroll
  for (int pass = 0; pass < 2; ++pass) {
    if (__any(gm > tmin)) {            // wave-uniform branch
      if (gm > tmin) {                 // per-lane insert (keys unique by oct id)
        ins8(tk, tmin, tmpos, gm);
        #pragma unroll
        for (int j = 0; j < 8; ++j) if (kv[j] == gm) kv[j] = 0u;
      }
      gm = umax8(kv);
    }
  }
  if (__any(gm > tmin)) {              // rare: >=3 qualifiers in this group
    #pragma unroll
    for (int j = 0; j < 8; ++j) if (kv[j] > tmin) ins8(tk, tmin, tmpos, kv[j]);
  }
}

// LDS key array XOR swizzle (u32 granularity, keeps uint4 alignment):
// bijective (XOR touches bits 2-4 only; off>>6 untouched); spreads the
// stride-64 phase-2 reads across bank groups.
__device__ __forceinline__ int kswz(int row, int off) {
  return row * 512 + (off ^ (((off >> 6) & 7) << 2));
}
__device__ __forceinline__ void ld8swz(const unsigned* k, int row, int off,
                                       unsigned kv[8]) {
  uint4 ka = *(const uint4*)&k[kswz(row, off)];
  uint4 kb = *(const uint4*)&k[kswz(row, off + 4)];
  kv[0] = ka.x; kv[1] = ka.y; kv[2] = ka.z; kv[3] = ka.w;
  kv[4] = kb.x; kv[5] = kb.y; kv[6] = kb.z; kv[7] = kb.w;
}

// ---------------- Kernel 1: fused Q/K projection (fp32 + bf16 row-major) ----
__global__ __launch_bounds__(512, 2) void qk_proj(
    const float* __restrict__ x, const float* __restrict__ Wq,
    const float* __restrict__ Wk, float* __restrict__ Qt,
    float* __restrict__ Kt, unsigned short* __restrict__ Qh,
    unsigned short* __restrict__ Kh) {
  __shared__ float4 xs4[64][65];  // row stride 65 f4-units -> bank-group spread
  const int t = threadIdx.x;
  const int rb = blockIdx.x;      // 256 blocks of 64 rows
  {
    const float4* xg = (const float4*)(x + (size_t)rb * 64 * CDIM);
    #pragma unroll
    for (int i = 0; i < 8; ++i) {
      int idx = i * 512 + t;      // 0..4095
      xs4[idx >> 6][idx & 63] = xg[idx];
    }
  }
  __syncthreads();

  const int lane = t & 63;
  const int wu = __builtin_amdgcn_readfirstlane(t >> 6);  // wave id, uniform
  const int proj = wu >> 2;
  const int chunk = wu & 3;       // d-chunk: d = chunk*16 .. +15
  const float* __restrict__ Wp = proj ? Wk : Wq;

  float acc[16];
  #pragma unroll
  for (int j = 0; j < 16; ++j) acc[j] = 0.f;

  #pragma unroll 4
  for (int cs = 0; cs < 64; ++cs) {        // 4 c's per step
    float4 xv = xs4[lane][cs];
    const float xc[4] = {xv.x, xv.y, xv.z, xv.w};
    #pragma unroll
    for (int i = 0; i < 4; ++i) {
      const float4* __restrict__ w4 =
          (const float4*)(Wp + (size_t)(cs * 4 + i) * DKDIM + chunk * 16);
      float4 wa = w4[0], wb = w4[1], wc = w4[2], wd = w4[3];
      float xi = xc[i];
      acc[0]  = fmaf(xi, wa.x, acc[0]);  acc[1]  = fmaf(xi, wa.y, acc[1]);
      acc[2]  = fmaf(xi, wa.z, acc[2]);  acc[3]  = fmaf(xi, wa.w, acc[3]);
      acc[4]  = fmaf(xi, wb.x, acc[4]);  acc[5]  = fmaf(xi, wb.y, acc[5]);
      acc[6]  = fmaf(xi, wb.z, acc[6]);  acc[7]  = fmaf(xi, wb.w, acc[7]);
      acc[8]  = fmaf(xi, wc.x, acc[8]);  acc[9]  = fmaf(xi, wc.y, acc[9]);
      acc[10] = fmaf(xi, wc.z, acc[10]); acc[11] = fmaf(xi, wc.w, acc[11]);
      acc[12] = fmaf(xi, wd.x, acc[12]); acc[13] = fmaf(xi, wd.y, acc[13]);
      acc[14] = fmaf(xi, wd.z, acc[14]); acc[15] = fmaf(xi, wd.w, acc[15]);
    }
  }

  const int gr = rb * 64 + lane;  // global row
  float* Of = (proj ? Kt : Qt) + (size_t)gr * 64 + chunk * 16;
  #pragma unroll
  for (int i = 0; i < 4; ++i) {
    float4 o = {acc[4 * i], acc[4 * i + 1], acc[4 * i + 2], acc[4 * i + 3]};
    ((float4*)Of)[i] = o;
  }
  unsigned short* Oh = (proj ? Kh : Qh) + (size_t)gr * 64 + chunk * 16;
  unsigned hp[8];
  #pragma unroll
  for (int i = 0; i < 8; ++i)
    hp[i] = (unsigned)f2bf(acc[2 * i]) | ((unsigned)f2bf(acc[2 * i + 1]) << 16);
  uint4 h0 = {hp[0], hp[1], hp[2], hp[3]};
  uint4 h1 = {hp[4], hp[5], hp[6], hp[7]};
  ((uint4*)Oh)[0] = h0;
  ((uint4*)Oh)[1] = h1;
}

// ---------------- Kernel 2: FUSED, oct-max funnel (depth 16) ----------------
// Identical to round 7 except ONE change: phase 4a uses PLAIN stores instead
// of __builtin_nontemporal_store. Counter evidence (r4: 1.5 TB/s, r7: 1.6
// TB/s apparent write BW vs fillBufferAligned's 5.4 TB/s with plain stores):
// nt (no-allocate) stores bypass L2 write-combining and hit HBM as 16 B
// partial-line writes, quartering write BW (6.3/4 = 1.6 TB/s -- exact match).
// Plain stores let L2 absorb + write back full 64 B lines.
__global__ __launch_bounds__(256, 4) void s_fused(
    const unsigned short* __restrict__ Qh, const unsigned short* __restrict__ Kh,
    const float* __restrict__ Qt, const float* __restrict__ Kt,
    float* __restrict__ out) {
  __shared__ unsigned keys[16 * 512];   // 32 KB, XOR-swizzled oct-keys
  __shared__ unsigned cand[16][64];     // 4 KB survivors
  float (*pval)[8] = (float(*)[8])keys;          // overlay (keys dead after ph2)
  int   (*pcol)[8] = (int(*)[8])(keys + 128);

  const int t = threadIdx.x;
  const int lane = t & 63;
  const int wu = __builtin_amdgcn_readfirstlane(t >> 6);
  // XCD-chunked bijective swizzle (1024 = 8*128)
  const int bid = blockIdx.x;
  const int orig = (bid & 7) * 128 + (bid >> 3);
  const int blockrow = orig * 16;  // global row base
  const int b = blockrow >> 12;    // batch

  const int l15 = lane & 15, lk = lane >> 4;
  // A-fragments: the block's 16 Q rows. row = lane&15, k = (lane>>4)*8+j.
  const int rowg = blockrow + l15;
  const short8v a0 = *(const short8v*)(Qh + (size_t)rowg * 64 + lk * 8);
  const short8v a1 = *(const short8v*)(Qh + (size_t)rowg * 64 + lk * 8 + 32);
  const unsigned short* Kb = Kh + ((size_t)(b << 12)) * 64;

  // ---- Phase 1: MFMA + oct-max over my 1024-col slice (no selection) ----
  unsigned okey[4][8];             // [stream i][group g]
  #pragma unroll 1
  for (int g = 0; g < 8; ++g) {
    float om[4];
    #pragma unroll
    for (int t8 = 0; t8 < 8; ++t8) {
      const int col = wu * 1024 + g * 128 + t8 * 16 + l15;
      const unsigned short* kp = Kb + (size_t)col * 64 + lk * 8;
      const short8v b0 = *(const short8v*)(kp);        // B: col=lane&15, k-half 0
      const short8v b1 = *(const short8v*)(kp + 32);   // k-half 1
      f32x4 acc = {0.f, 0.f, 0.f, 0.f};
      acc = __builtin_amdgcn_mfma_f32_16x16x32_bf16(a0, b0, acc, 0, 0, 0);
      acc = __builtin_amdgcn_mfma_f32_16x16x32_bf16(a1, b1, acc, 0, 0, 0);
      // C/D: col=lane&15, row=(lane>>4)*4+i (m89-verified)
      #pragma unroll
      for (int i = 0; i < 4; ++i)
        om[i] = (t8 == 0) ? acc[i] : fmaxf(om[i], acc[i]);
    }
    const unsigned oid = (unsigned)(((wu * 8 + g) << 4) | l15);  // 9 bits
    #pragma unroll
    for (int i = 0; i < 4; ++i)
      okey[i][g] = (mono(om[i]) & 0xFFFFFE00u) | oid;  // 23 value bits
  }
  #pragma unroll
  for (int i = 0; i < 4; ++i) {    // write 8 oct-keys per stream
    const int row = lk * 4 + i;
    const int off = wu * 128 + l15 * 8;
    uint4 s0 = {okey[i][0], okey[i][1], okey[i][2], okey[i][3]};
    uint4 s1 = {okey[i][4], okey[i][5], okey[i][6], okey[i][7]};
    *(uint4*)&keys[kswz(row, off)] = s0;
    *(uint4*)&keys[kswz(row, off + 4)] = s1;
  }
  __syncthreads();

  // ---- Phase 2: 8 scan-lanes/row, each scans a 64-key span -> 64 surv/row --
  if ((t & 15) < 8) {
    const int row = t >> 4, s = t & 7;
    const int base = s * 64;
    unsigned kv[8]; unsigned mt[8]; unsigned mmin; int mmpos;
    ld8swz(keys, row, base, kv);
    seed8r(kv, mt, mmin, mmpos);
    #pragma unroll
    for (int m = 1; m < 8; ++m) {
      ld8swz(keys, row, base + m * 8, kv);
      scan8r(kv, mt, mmin, mmpos);
    }
    uint4 o0 = {mt[0], mt[1], mt[2], mt[3]};
    uint4 o1 = {mt[4], mt[5], mt[6], mt[7]};
    uint4* cp = (uint4*)(&cand[row][s * 8]);
    cp[0] = o0; cp[1] = o1;
  }
  __syncthreads();

  // ---- Phase 3: top-16 octs -> 128 cols -> exact recompute + softmax ----
  #pragma unroll 1
  for (int p = 0; p < 4; ++p) {
    const int rr = p * 4 + wu;     // my wave's row this pass
    unsigned ok = cand[rr][lane];
    const int q2 = lane >> 2, e2 = lane & 3;  // oct rank / col pair within oct
    unsigned mykey = 0u;
    #pragma unroll
    for (int it = 0; it < 16; ++it) {  // branchless: keys unique -> self-zero
      unsigned m = ok;
      #pragma unroll
      for (int d = 1; d < 64; d <<= 1) m = umaxu(m, (unsigned)__shfl_xor((int)m, d, 64));
      if (q2 == it) mykey = m;         // lane group q2 takes winner #it
      if (ok == m) ok = 0u;
    }
    const unsigned oid = mykey & 0x1FFu;
    const int colb = (int)((oid >> 4) * 128 + (oid & 15u));
    const int col0 = colb + e2 * 16;   // t8 = e2
    const int col1 = col0 + 64;        // t8 = e2 + 4
    const float4* Kp0 = (const float4*)(Kt + ((size_t)((b << 12) + col0)) * 64);
    const float4* Kp1 = (const float4*)(Kt + ((size_t)((b << 12) + col1)) * 64);
    const float4* Qp = (const float4*)(Qt + (size_t)(blockrow + rr) * 64);  // uniform
    float s0 = 0.f, s1 = 0.f;
    #pragma unroll
    for (int g2 = 0; g2 < 16; ++g2) {  // same sequential fma order per column
      float4 qf = Qp[g2];
      float4 k0f = Kp0[g2];
      float4 k1f = Kp1[g2];
      s0 = fmaf(qf.x, k0f.x, s0); s1 = fmaf(qf.x, k1f.x, s1);
      s0 = fmaf(qf.y, k0f.y, s0); s1 = fmaf(qf.y, k1f.y, s1);
      s0 = fmaf(qf.z, k0f.z, s0); s1 = fmaf(qf.z, k1f.z, s1);
      s0 = fmaf(qf.w, k0f.w, s0); s1 = fmaf(qf.w, k1f.w, s1);
    }
    unsigned k0 = mono(s0), k1 = mono(s1);  // full precision: exact ordering
    float vals[8]; int cols[8];
    #pragma unroll
    for (int it = 0; it < 8; ++it) {
      unsigned m = umaxu(k0, k1);
      #pragma unroll
      for (int d = 1; d < 64; d <<= 1) m = umaxu(m, (unsigned)__shfl_xor((int)m, d, 64));
      unsigned long long win = __ballot(k0 == m || k1 == m);
      int wl = (int)__ffsll(win) - 1;
      int mycol = (k0 == m) ? col0 : col1;   // slot resolved on owner lane
      cols[it] = __shfl(mycol, wl, 64);
      vals[it] = unmono(m);
      if (lane == wl) { if (k0 == m) k0 = 0u; else k1 = 0u; }  // exclude winner
    }
    float vq[8]; float sum = 0.f;
    #pragma unroll
    for (int it = 0; it < 8; ++it) { vq[it] = __expf((vals[it] - vals[0]) * SCALE); sum += vq[it]; }
    float inv = 1.f / sum;
    if (lane < 8) {
      pval[rr][lane] = vq[lane] * inv;
      pcol[rr][lane] = cols[lane];
    }
  }
  // no barrier: phase 4 rows {wu, wu+4, wu+8, wu+12} were produced by this wave

  // ---- Phase 4a: PLAIN zero-fill of my wave's 4 rows (L2 write-combined) ----
  {
    const v4f z = {0.f, 0.f, 0.f, 0.f};
    #pragma unroll 1
    for (int j = 0; j < 4; ++j) {
      const int sr = wu + 4 * j;
      v4f* orow4 = (v4f*)(out + ((size_t)(blockrow + sr) << 12));
      #pragma unroll
      for (int i = 0; i < 16; ++i)
        orow4[(size_t)i * 64 + lane] = z;
    }
  }
  // drain fill stores (per-wave) so the sparse patch lands after them
  asm volatile("s_waitcnt vmcnt(0)" ::: "memory");
  // ---- Phase 4b: sparse patch by the same wave that filled the rows ----
  if (lane < 32) {
    const int sr = wu + 4 * (lane >> 3);
    const int q = lane & 7;
    out[((size_t)(blockrow + sr) << 12) + (size_t)pcol[sr][q]] = pval[sr][q];
  }
}

extern "C" void kernel_launch(void* const* d_in, const int* in_sizes, int n_in,
                              void* d_out, int out_size, void* d_ws, size_t ws_size,
                              hipStream_t stream) {
  const float* x  = (const float*)d_in[0];
  const float* Wq = (const float*)d_in[1];
  const float* Wk = (const float*)d_in[2];
  float* out = (float*)d_out;

  char* ws = (char*)d_ws;                       // 12 MB used
  float* Qt = (float*)ws;                       // 4 MB fp32 [row][64]
  float* Kt = (float*)(ws + ((size_t)4 << 20)); // 4 MB
  unsigned short* Qh = (unsigned short*)(ws + ((size_t)8 << 20));   // 2 MB bf16
  unsigned short* Kh = (unsigned short*)(ws + ((size_t)10 << 20));  // 2 MB

  qk_proj<<<dim3(NROW / 64), 512, 0, stream>>>(x, Wq, Wk, Qt, Kt, Qh, Kh);
  s_fused<<<1024, 256, 0, stream>>>(Qh, Kh, Qt, Kt, out);
}